// Round 1
// baseline (719.710 us; speedup 1.0000x reference)
//
#include <hip/hip_runtime.h>
#include <stdint.h>

#define NB 16
#define CC 64
#define HH 256
#define WW 256
#define HP 258
#define WP 258

// ---- pack weights: bit c of word (o,kh,kw) = (w[o][c][kh][kw] < 0) ----
__global__ __launch_bounds__(256) void pack_w_kernel(const float* __restrict__ w,
                                                     uint64_t* __restrict__ pW) {
    int widx = (blockIdx.x * 256 + threadIdx.x) >> 6;  // one packed word per wave
    int lane = threadIdx.x & 63;                       // lane = input channel
    if (widx >= CC * 9) return;
    int o = widx / 9;
    int t = widx % 9;
    float v = w[(size_t)o * (CC * 9) + (size_t)lane * 9 + t];
    unsigned long long m = __ballot(v < 0.0f);
    if (lane == 0) pW[widx] = m;
}

// ---- pack activations: pX[n][h+1][w+1] = 64 channel sign bits (1 = negative) ----
__global__ __launch_bounds__(256) void pack_x_kernel(const float* __restrict__ x,
                                                     uint64_t* __restrict__ pX) {
    int g = blockIdx.x * 256 + threadIdx.x;  // 4-pixel group within image, 0..16383
    int n = blockIdx.y;
    const float4* xv = (const float4*)x;
    uint64_t b0 = 0, b1 = 0, b2 = 0, b3 = 0;
#pragma unroll 16
    for (int c = 0; c < CC; ++c) {
        float4 v = xv[((size_t)(n * CC + c) << 14) + g];  // coalesced: lanes contiguous in w
        b0 |= (uint64_t)(v.x < 0.0f) << c;
        b1 |= (uint64_t)(v.y < 0.0f) << c;
        b2 |= (uint64_t)(v.z < 0.0f) << c;
        b3 |= (uint64_t)(v.w < 0.0f) << c;
    }
    int px = g << 2;
    int h = px >> 8;
    int w = px & 255;
    uint64_t* dst = pX + ((size_t)n * HP + (h + 1)) * WP + (w + 1);
    dst[0] = b0; dst[1] = b1; dst[2] = b2; dst[3] = b3;
}

// ---- binary conv (xnor-popcount) + bias + relu + eval BN ----
// block = (n, 4-row group). Stages 6 padded rows in LDS once, shared by all 64 o.
// lane = o -> LDS reads are wave-uniform broadcasts (conflict-free).
__global__ __launch_bounds__(256) void bconv_kernel(const uint64_t* __restrict__ pX,
                                                    const uint64_t* __restrict__ pW,
                                                    const float* __restrict__ bias,
                                                    const float* __restrict__ gamma,
                                                    const float* __restrict__ beta,
                                                    const float* __restrict__ rmean,
                                                    const float* __restrict__ rvar,
                                                    float* __restrict__ out) {
    __shared__ uint64_t tile[6 * WP];  // 12.4 KiB
    int blk = blockIdx.x;              // 0..1023
    int n = blk >> 6;
    int hq = blk & 63;
    int tid = threadIdx.x;

    const uint64_t* src = pX + ((size_t)n * HP + hq * 4) * WP;
    for (int i = tid; i < 6 * WP; i += 256) tile[i] = src[i];

    int o = tid & 63;        // lane = output channel
    int wid = tid >> 6;      // wave = row within 4-row group
    int h = hq * 4 + wid;

    // per-lane weights + pad-tap corrections (pad word is 0 -> spurious 64-2*popc(W))
    uint64_t q[9];
    int ct[9];
#pragma unroll
    for (int t = 0; t < 9; ++t) {
        q[t] = pW[o * 9 + t];
        ct[t] = 64 - 2 * __popcll(q[t]);
    }
    int top = ct[0] + ct[1] + ct[2], bot = ct[6] + ct[7] + ct[8];
    int left = ct[0] + ct[3] + ct[6], right = ct[2] + ct[5] + ct[8];
    int hcorr = (h == 0 ? top : 0) + (h == 255 ? bot : 0);
    int cL = left  - (h == 0 ? ct[0] : 0) - (h == 255 ? ct[6] : 0);
    int cR = right - (h == 0 ? ct[2] : 0) - (h == 255 ? ct[8] : 0);

    float bo = bias[o];
    float inv = gamma[o] / sqrtf(rvar[o] + 1e-5f);
    float addc = beta[o] - rmean[o] * inv;

    __syncthreads();

    const uint64_t* r0 = &tile[wid * WP];
    const uint64_t* r1 = r0 + WP;
    const uint64_t* r2 = r1 + WP;

    // sliding 3-col window: a* = col w, e* = col w+1, c* = col w+2 (padded coords)
    uint64_t a0 = r0[0], a1 = r1[0], a2 = r2[0];
    uint64_t e0 = r0[1], e1 = r1[1], e2 = r2[1];

    float4* out4 = (float4*)out;
    size_t obase = ((size_t)(n * CC + o) << 14) + (size_t)h * 64;

    for (int wg = 0; wg < 64; ++wg) {
        float res[4];
#pragma unroll
        for (int j = 0; j < 4; ++j) {
            int wpx = wg * 4 + j;
            uint64_t c0 = r0[wpx + 2], c1 = r1[wpx + 2], c2 = r2[wpx + 2];
            int p = __popcll(a0 ^ q[0]) + __popcll(e0 ^ q[1]) + __popcll(c0 ^ q[2])
                  + __popcll(a1 ^ q[3]) + __popcll(e1 ^ q[4]) + __popcll(c1 ^ q[5])
                  + __popcll(a2 ^ q[6]) + __popcll(e2 ^ q[7]) + __popcll(c2 ^ q[8]);
            int corr = hcorr;
            if (wpx == 0)   corr += cL;
            if (wpx == 255) corr += cR;
            float yf = (float)(576 - 2 * p - corr) + bo;
            yf = fmaxf(yf, 0.0f);
            res[j] = fmaf(yf, inv, addc);
            a0 = e0; a1 = e1; a2 = e2;
            e0 = c0; e1 = c1; e2 = c2;
        }
        out4[obase + wg] = make_float4(res[0], res[1], res[2], res[3]);
    }
}

extern "C" void kernel_launch(void* const* d_in, const int* in_sizes, int n_in,
                              void* d_out, int out_size, void* d_ws, size_t ws_size,
                              hipStream_t stream) {
    const float* x     = (const float*)d_in[0];
    const float* w     = (const float*)d_in[1];
    const float* bias  = (const float*)d_in[2];
    const float* gamma = (const float*)d_in[3];
    const float* beta  = (const float*)d_in[4];
    const float* rmean = (const float*)d_in[5];
    const float* rvar  = (const float*)d_in[6];
    float* out = (float*)d_out;

    uint64_t* pX = (uint64_t*)d_ws;
    size_t pXwords = (size_t)NB * HP * WP;        // ~8.5 MiB
    uint64_t* pW = pX + pXwords;                  // 576 words

    hipMemsetAsync(pX, 0, pXwords * sizeof(uint64_t), stream);  // zero pads
    pack_w_kernel<<<(CC * 9 + 3) / 4, 256, 0, stream>>>(w, pW);
    pack_x_kernel<<<dim3(64, NB), 256, 0, stream>>>(x, pX);
    bconv_kernel<<<NB * 64, 256, 0, stream>>>(pX, pW, bias, gamma, beta, rmean, rvar, out);
}

// Round 2
// 533.751 us; speedup vs baseline: 1.3484x; 1.3484x over previous
//
#include <hip/hip_runtime.h>
#include <stdint.h>

#define NB 16
#define CC 64
#define HH 256
#define WW 256
#define HP 258
#define WP 258

// ---- pack weights: bit c of word (o,kh,kw) = (w[o][c][kh][kw] < 0) ----
__global__ __launch_bounds__(256) void pack_w_kernel(const float* __restrict__ w,
                                                     uint64_t* __restrict__ pW) {
    int widx = (blockIdx.x * 256 + threadIdx.x) >> 6;  // one packed word per wave
    int lane = threadIdx.x & 63;                       // lane = input channel
    if (widx >= CC * 9) return;
    int o = widx / 9;
    int t = widx % 9;
    float v = w[(size_t)o * (CC * 9) + (size_t)lane * 9 + t];
    unsigned long long m = __ballot(v < 0.0f);
    if (lane == 0) pW[widx] = m;
}

// ---- zero only the pad cells of pX (rows 0,257 and cols 0,257 per image) ----
__global__ __launch_bounds__(256) void zero_pad_kernel(uint64_t* __restrict__ pX) {
    int idx = blockIdx.x * 256 + threadIdx.x;
    if (idx >= NB * 1028) return;
    int n = idx / 1028;
    int r = idx % 1028;
    size_t base = (size_t)n * HP * WP;
    size_t off;
    if (r < 258) off = (size_t)r;                             // top pad row
    else if (r < 516) off = (size_t)257 * WP + (r - 258);     // bottom pad row
    else {
        int rr = r - 516;                                     // 0..511
        off = (size_t)(1 + (rr >> 1)) * WP + ((rr & 1) ? 257 : 0);
    }
    pX[base + off] = 0;
}

// ---- pack activations: pX[n][h+1][w+1] = 64 channel sign bits (1 = negative) ----
__global__ __launch_bounds__(256) void pack_x_kernel(const float* __restrict__ x,
                                                     uint64_t* __restrict__ pX) {
    int g = blockIdx.x * 256 + threadIdx.x;  // 4-pixel group within image, 0..16383
    int n = blockIdx.y;
    const float4* xv = (const float4*)x;
    uint64_t b0 = 0, b1 = 0, b2 = 0, b3 = 0;
#pragma unroll 16
    for (int c = 0; c < CC; ++c) {
        float4 v = xv[((size_t)(n * CC + c) << 14) + g];  // coalesced: lanes contiguous in w
        b0 |= (uint64_t)(v.x < 0.0f) << c;
        b1 |= (uint64_t)(v.y < 0.0f) << c;
        b2 |= (uint64_t)(v.z < 0.0f) << c;
        b3 |= (uint64_t)(v.w < 0.0f) << c;
    }
    int px = g << 2;
    int h = px >> 8;
    int w = px & 255;
    uint64_t* dst = pX + ((size_t)n * HP + (h + 1)) * WP + (w + 1);
    dst[0] = b0; dst[1] = b1; dst[2] = b2; dst[3] = b3;
}

// ---- binary conv (xnor-popcount) + bias + relu + eval BN ----
// Block = (n, 4-row group), 256 threads. Wave wid -> output row h; lane l ->
// pixel quad 4l..4l+3. X window (3 rows x 8 u64) loaded once into VGPRs from
// the padded global buffer. Loop over o is wave-uniform -> weights come in
// via s_load / SGPRs; stores are 1KB contiguous per wave (full lines, no
// write amplification).
__global__ __launch_bounds__(256) void bconv_kernel(const uint64_t* __restrict__ pX,
                                                    const uint64_t* __restrict__ pW,
                                                    const float* __restrict__ bias,
                                                    const float* __restrict__ gamma,
                                                    const float* __restrict__ beta,
                                                    const float* __restrict__ rmean,
                                                    const float* __restrict__ rvar,
                                                    float* __restrict__ out) {
    int blk = blockIdx.x;            // 0..1023
    int n = blk >> 6;
    int hq = blk & 63;
    int tid = threadIdx.x;
    int l = tid & 63;                // lane -> pixel quad
    int wid = tid >> 6;              // wave -> row within 4-row group
    int h = hq * 4 + wid;            // output row; padded rows h..h+2

    // Load X window: 3 padded rows, cols 4l..4l+7 (need 4l..4l+6; 8th is slack,
    // stays within ws because pW follows pX). 16B-aligned: row stride 2064B, 32l B.
    uint64_t xw[3][8];
    const uint64_t* rowp = pX + ((size_t)n * HP + h) * WP + 4 * l;
#pragma unroll
    for (int r = 0; r < 3; ++r) {
        const ulonglong2* p2 = (const ulonglong2*)(rowp + (size_t)r * WP);
        ulonglong2 a = p2[0], b = p2[1], c = p2[2], d = p2[3];
        xw[r][0] = a.x; xw[r][1] = a.y; xw[r][2] = b.x; xw[r][3] = b.y;
        xw[r][4] = c.x; xw[r][5] = c.y; xw[r][6] = d.x; xw[r][7] = d.y;
    }

    int isL = (l == 0);
    int isR = (l == 63);
    float4* out4 = (float4*)out;
    size_t obase = ((size_t)(n * CC) << 14) + (size_t)h * 64 + l;

    for (int o = 0; o < CC; ++o) {
        // wave-uniform weight fetch -> SGPRs
        uint64_t q[9];
        int ct[9];
#pragma unroll
        for (int t = 0; t < 9; ++t) {
            q[t] = pW[o * 9 + t];
            ct[t] = 64 - 2 * __popcll(q[t]);   // pad-tap correction (pad word = 0)
        }
        int top = ct[0] + ct[1] + ct[2], bot = ct[6] + ct[7] + ct[8];
        int left = ct[0] + ct[3] + ct[6], right = ct[2] + ct[5] + ct[8];
        int hcorr = (h == 0 ? top : 0) + (h == 255 ? bot : 0);
        int cL = left  - (h == 0 ? ct[0] : 0) - (h == 255 ? ct[6] : 0);
        int cR = right - (h == 0 ? ct[2] : 0) - (h == 255 ? ct[8] : 0);

        float bo = bias[o];
        float inv = gamma[o] / sqrtf(rvar[o] + 1e-5f);
        float addc = beta[o] - rmean[o] * inv;

        float4 res;
        float* resp = (float*)&res;
#pragma unroll
        for (int j = 0; j < 4; ++j) {
            int p = 0;
#pragma unroll
            for (int r = 0; r < 3; ++r) {
                p += __popcll(xw[r][j]     ^ q[r * 3])
                   + __popcll(xw[r][j + 1] ^ q[r * 3 + 1])
                   + __popcll(xw[r][j + 2] ^ q[r * 3 + 2]);
            }
            int corr = hcorr;
            if (j == 0 && isL) corr += cL;
            if (j == 3 && isR) corr += cR;
            float yf = (float)(576 - 2 * p - corr) + bo;
            yf = fmaxf(yf, 0.0f);
            resp[j] = fmaf(yf, inv, addc);
        }
        out4[obase + ((size_t)o << 14)] = res;  // wave store: 1KB contiguous
    }
}

extern "C" void kernel_launch(void* const* d_in, const int* in_sizes, int n_in,
                              void* d_out, int out_size, void* d_ws, size_t ws_size,
                              hipStream_t stream) {
    const float* x     = (const float*)d_in[0];
    const float* w     = (const float*)d_in[1];
    const float* bias  = (const float*)d_in[2];
    const float* gamma = (const float*)d_in[3];
    const float* beta  = (const float*)d_in[4];
    const float* rmean = (const float*)d_in[5];
    const float* rvar  = (const float*)d_in[6];
    float* out = (float*)d_out;

    uint64_t* pX = (uint64_t*)d_ws;
    size_t pXwords = (size_t)NB * HP * WP;        // ~8.5 MiB
    uint64_t* pW = pX + pXwords;                  // 576 words

    zero_pad_kernel<<<(NB * 1028 + 255) / 256, 256, 0, stream>>>(pX);
    pack_w_kernel<<<(CC * 9 + 3) / 4, 256, 0, stream>>>(w, pW);
    pack_x_kernel<<<dim3(64, NB), 256, 0, stream>>>(x, pX);
    bconv_kernel<<<NB * 64, 256, 0, stream>>>(pX, pW, bias, gamma, beta, rmean, rvar, out);
}

// Round 3
// 514.743 us; speedup vs baseline: 1.3982x; 1.0369x over previous
//
#include <hip/hip_runtime.h>
#include <stdint.h>

#define NB 16
#define CC 64
#define HH 256
#define WW 256
#define HP 258
#define WP 258

// ---- pack weights: bit c of word (o,kh,kw) = (w[o][c][kh][kw] < 0) ----
__global__ __launch_bounds__(256) void pack_w_kernel(const float* __restrict__ w,
                                                     uint64_t* __restrict__ pW) {
    int widx = (blockIdx.x * 256 + threadIdx.x) >> 6;  // one packed word per wave
    int lane = threadIdx.x & 63;                       // lane = input channel
    if (widx >= CC * 9) return;
    int o = widx / 9;
    int t = widx % 9;
    float v = w[(size_t)o * (CC * 9) + (size_t)lane * 9 + t];
    unsigned long long m = __ballot(v < 0.0f);
    if (lane == 0) pW[widx] = m;
}

// ---- pack activations + zero the pad ring (side job of blockIdx.x==0) ----
__global__ __launch_bounds__(256) void pack_x_kernel(const float* __restrict__ x,
                                                     uint64_t* __restrict__ pX) {
    int n = blockIdx.y;
    if (blockIdx.x == 0) {  // zero this image's 1028 pad words
        for (int r = threadIdx.x; r < 1028; r += 256) {
            size_t base = (size_t)n * HP * WP;
            size_t off;
            if (r < 258) off = (size_t)r;                          // top pad row
            else if (r < 516) off = (size_t)257 * WP + (r - 258);  // bottom pad row
            else {
                int rr = r - 516;                                  // 0..511 -> side cols
                off = (size_t)(1 + (rr >> 1)) * WP + ((rr & 1) ? 257 : 0);
            }
            pX[base + off] = 0;
        }
    }
    int g = blockIdx.x * 256 + threadIdx.x;  // 4-pixel group within image, 0..16383
    const float4* xv = (const float4*)x;
    uint64_t b0 = 0, b1 = 0, b2 = 0, b3 = 0;
#pragma unroll 16
    for (int c = 0; c < CC; ++c) {
        float4 v = xv[((size_t)(n * CC + c) << 14) + g];  // coalesced: lanes contiguous in w
        b0 |= (uint64_t)(v.x < 0.0f) << c;
        b1 |= (uint64_t)(v.y < 0.0f) << c;
        b2 |= (uint64_t)(v.z < 0.0f) << c;
        b3 |= (uint64_t)(v.w < 0.0f) << c;
    }
    int px = g << 2;
    int h = px >> 8;
    int w = px & 255;
    uint64_t* dst = pX + ((size_t)n * HP + (h + 1)) * WP + (w + 1);
    dst[0] = b0; dst[1] = b1; dst[2] = b2; dst[3] = b3;
}

// ---- binary conv (xnor-popcount) + bias + relu + eval BN ----
// Block = (n, 4-row group). Wave wid -> row h; lane l -> pixel quad 4l..4l+3.
// Per-o constants (packed W, border corrections, epilogue floats) are computed
// ONCE per block by lanes 0..63 into LDS; the o-loop reads them with uniform
// addresses (broadcast, conflict-free) instead of per-iteration scalar-load
// stalls. X window: 3 rows x 6 u64 in VGPRs. Stores: 1KB contiguous per wave.
__global__ __launch_bounds__(256, 4) void bconv_kernel(const uint64_t* __restrict__ pX,
                                                       const uint64_t* __restrict__ pW,
                                                       const float* __restrict__ bias,
                                                       const float* __restrict__ gamma,
                                                       const float* __restrict__ beta,
                                                       const float* __restrict__ rmean,
                                                       const float* __restrict__ rvar,
                                                       float* __restrict__ out) {
    __shared__ uint64_t sq[CC][9];  // packed weights
    __shared__ int si[CC][8];       // top,bot,left,right,ct0,ct2,ct6,ct8
    __shared__ float sf[CC][3];     // bias, inv, addc

    int tid = threadIdx.x;
    if (tid < CC) {
        int o = tid;
        int ct[9];
#pragma unroll
        for (int t = 0; t < 9; ++t) {
            uint64_t q = pW[o * 9 + t];
            sq[o][t] = q;
            ct[t] = 64 - 2 * __popcll(q);  // pad-tap correction (pad word = 0)
        }
        si[o][0] = ct[0] + ct[1] + ct[2];  // top
        si[o][1] = ct[6] + ct[7] + ct[8];  // bot
        si[o][2] = ct[0] + ct[3] + ct[6];  // left
        si[o][3] = ct[2] + ct[5] + ct[8];  // right
        si[o][4] = ct[0]; si[o][5] = ct[2]; si[o][6] = ct[6]; si[o][7] = ct[8];
        float inv = gamma[o] / sqrtf(rvar[o] + 1e-5f);
        sf[o][0] = bias[o];
        sf[o][1] = inv;
        sf[o][2] = beta[o] - rmean[o] * inv;
    }

    int blk = blockIdx.x;  // 0..1023
    int n = blk >> 6;
    int hq = blk & 63;
    int l = tid & 63;      // lane -> pixel quad
    int wid = tid >> 6;    // wave -> row within 4-row group
    int h = hq * 4 + wid;  // output row; padded rows h..h+2

    // X window: 3 padded rows, cols 4l..4l+5 (outputs 4l+j need cols 4l+j..4l+j+2, j<=3)
    uint64_t xw[3][6];
    const uint64_t* rowp = pX + ((size_t)n * HP + h) * WP + 4 * l;
#pragma unroll
    for (int r = 0; r < 3; ++r) {
        const ulonglong2* p2 = (const ulonglong2*)(rowp + (size_t)r * WP);
        ulonglong2 a = p2[0], b = p2[1], c = p2[2];
        xw[r][0] = a.x; xw[r][1] = a.y; xw[r][2] = b.x;
        xw[r][3] = b.y; xw[r][4] = c.x; xw[r][5] = c.y;
    }

    __syncthreads();

    bool isL = (l == 0), isR = (l == 63);
    bool isT = (h == 0), isB = (h == 255);
    float4* out4 = (float4*)out;
    size_t obase = ((size_t)(n * CC) << 14) + (size_t)h * 64 + l;

#pragma unroll 2
    for (int o = 0; o < CC; ++o) {
        uint64_t q0 = sq[o][0], q1 = sq[o][1], q2 = sq[o][2];
        uint64_t q3 = sq[o][3], q4 = sq[o][4], q5 = sq[o][5];
        uint64_t q6 = sq[o][6], q7 = sq[o][7], q8 = sq[o][8];
        int hcorr = 0, cL = si[o][2], cR = si[o][3];
        if (isT) { hcorr += si[o][0]; cL -= si[o][4]; cR -= si[o][5]; }
        if (isB) { hcorr += si[o][1]; cL -= si[o][6]; cR -= si[o][7]; }
        float bo = sf[o][0], inv = sf[o][1], addc = sf[o][2];

        float4 res;
        float* resp = (float*)&res;
#pragma unroll
        for (int j = 0; j < 4; ++j) {
            int p = __popcll(xw[0][j] ^ q0) + __popcll(xw[0][j + 1] ^ q1) + __popcll(xw[0][j + 2] ^ q2)
                  + __popcll(xw[1][j] ^ q3) + __popcll(xw[1][j + 1] ^ q4) + __popcll(xw[1][j + 2] ^ q5)
                  + __popcll(xw[2][j] ^ q6) + __popcll(xw[2][j + 1] ^ q7) + __popcll(xw[2][j + 2] ^ q8);
            int corr = hcorr;
            if (j == 0 && isL) corr += cL;
            if (j == 3 && isR) corr += cR;
            float yf = (float)(576 - 2 * p - corr) + bo;
            yf = fmaxf(yf, 0.0f);
            resp[j] = fmaf(yf, inv, addc);
        }
        out4[obase + ((size_t)o << 14)] = res;  // wave store: 1KB contiguous
    }
}

extern "C" void kernel_launch(void* const* d_in, const int* in_sizes, int n_in,
                              void* d_out, int out_size, void* d_ws, size_t ws_size,
                              hipStream_t stream) {
    const float* x     = (const float*)d_in[0];
    const float* w     = (const float*)d_in[1];
    const float* bias  = (const float*)d_in[2];
    const float* gamma = (const float*)d_in[3];
    const float* beta  = (const float*)d_in[4];
    const float* rmean = (const float*)d_in[5];
    const float* rvar  = (const float*)d_in[6];
    float* out = (float*)d_out;

    uint64_t* pX = (uint64_t*)d_ws;
    size_t pXwords = (size_t)NB * HP * WP;  // ~8.5 MiB
    uint64_t* pW = pX + pXwords;            // 576 words

    pack_w_kernel<<<(CC * 9 + 3) / 4, 256, 0, stream>>>(w, pW);
    pack_x_kernel<<<dim3(64, NB), 256, 0, stream>>>(x, pX);
    bconv_kernel<<<NB * 64, 256, 0, stream>>>(pX, pW, bias, gamma, beta, rmean, rvar, out);
}